// Round 1
// baseline (61.267 us; speedup 1.0000x reference)
//
#include <hip/hip_runtime.h>
#include <math.h>

#define D 2048
#define NROWS 16384

__global__ __launch_bounds__(256) void pal_row_theta(const float* __restrict__ recon,
                                                     const float* __restrict__ x,
                                                     float* __restrict__ theta) {
    const int row = blockIdx.x;
    const int tid = threadIdx.x;
    const float4* r4 = reinterpret_cast<const float4*>(recon + (size_t)row * D);
    const float4* x4 = reinterpret_cast<const float4*>(x + (size_t)row * D);

    float dot = 0.f, rr = 0.f, xx = 0.f;
#pragma unroll
    for (int k = 0; k < 2; ++k) {
        float4 a = r4[tid + k * 256];
        float4 b = x4[tid + k * 256];
        dot += a.x * b.x + a.y * b.y + a.z * b.z + a.w * b.w;
        rr  += a.x * a.x + a.y * a.y + a.z * a.z + a.w * a.w;
        xx  += b.x * b.x + b.y * b.y + b.z * b.z + b.w * b.w;
    }

    // 64-lane wave reduction
#pragma unroll
    for (int off = 32; off > 0; off >>= 1) {
        dot += __shfl_down(dot, off, 64);
        rr  += __shfl_down(rr,  off, 64);
        xx  += __shfl_down(xx,  off, 64);
    }

    __shared__ float s[3][4];
    const int wave = tid >> 6;
    const int lane = tid & 63;
    if (lane == 0) { s[0][wave] = dot; s[1][wave] = rr; s[2][wave] = xx; }
    __syncthreads();

    if (tid == 0) {
        float d = s[0][0] + s[0][1] + s[0][2] + s[0][3];
        float a = s[1][0] + s[1][1] + s[1][2] + s[1][3];
        float b = s[2][0] + s[2][1] + s[2][2] + s[2][3];
        float c = d / sqrtf(a * b);
        c = fminf(1.f, fmaxf(-1.f, c));
        theta[row] = acosf(c);
    }
}

__global__ __launch_bounds__(256) void pal_mean(const float* __restrict__ theta,
                                                float* __restrict__ out) {
    float s = 0.f;
    for (int i = threadIdx.x; i < NROWS; i += 256) s += theta[i];
#pragma unroll
    for (int off = 32; off > 0; off >>= 1) s += __shfl_down(s, off, 64);
    __shared__ float sh[4];
    const int wave = threadIdx.x >> 6;
    const int lane = threadIdx.x & 63;
    if (lane == 0) sh[wave] = s;
    __syncthreads();
    if (threadIdx.x == 0) {
        out[0] = (sh[0] + sh[1] + sh[2] + sh[3]) / (float)NROWS;
    }
}

extern "C" void kernel_launch(void* const* d_in, const int* in_sizes, int n_in,
                              void* d_out, int out_size, void* d_ws, size_t ws_size,
                              hipStream_t stream) {
    const float* recon = (const float*)d_in[0];
    const float* x     = (const float*)d_in[1];
    float* out   = (float*)d_out;
    float* theta = (float*)d_ws;   // NROWS floats = 64 KB scratch

    pal_row_theta<<<NROWS, 256, 0, stream>>>(recon, x, theta);
    pal_mean<<<1, 256, 0, stream>>>(theta, out);
}

// Round 2
// 47.454 us; speedup vs baseline: 1.2911x; 1.2911x over previous
//
#include <hip/hip_runtime.h>
#include <math.h>

#define D 2048
#define NROWS 16384
#define BLOCK 512           // 8 waves = 8 rows per block
#define WPB (BLOCK / 64)

__global__ __launch_bounds__(BLOCK) void pal_row_theta(const float* __restrict__ recon,
                                                       const float* __restrict__ x,
                                                       float* __restrict__ theta) {
    const int wave = threadIdx.x >> 6;
    const int lane = threadIdx.x & 63;
    const int row  = blockIdx.x * WPB + wave;

    const float4* r4 = reinterpret_cast<const float4*>(recon + (size_t)row * D);
    const float4* x4 = reinterpret_cast<const float4*>(x + (size_t)row * D);

    // 2048 floats = 512 float4 per row; 64 lanes x 8 float4 each.
    float dot = 0.f, rr = 0.f, xx = 0.f;
#pragma unroll
    for (int j = 0; j < 8; ++j) {
        float4 a = r4[lane + 64 * j];
        float4 b = x4[lane + 64 * j];
        dot += a.x * b.x + a.y * b.y + a.z * b.z + a.w * b.w;
        rr  += a.x * a.x + a.y * a.y + a.z * a.z + a.w * a.w;
        xx  += b.x * b.x + b.y * b.y + b.z * b.z + b.w * b.w;
    }

    // pure wave-level reduction: no LDS, no barriers
#pragma unroll
    for (int off = 32; off > 0; off >>= 1) {
        dot += __shfl_down(dot, off, 64);
        rr  += __shfl_down(rr,  off, 64);
        xx  += __shfl_down(xx,  off, 64);
    }

    if (lane == 0) {
        float c = dot / sqrtf(rr * xx);
        c = fminf(1.f, fmaxf(-1.f, c));
        theta[row] = acosf(c);
    }
}

__global__ __launch_bounds__(1024) void pal_mean(const float* __restrict__ theta,
                                                 float* __restrict__ out) {
    const float4* t4 = reinterpret_cast<const float4*>(theta);
    float s = 0.f;
#pragma unroll
    for (int k = 0; k < 4; ++k) {          // 16384/4 = 4096 float4 / 1024 threads
        float4 v = t4[threadIdx.x + 1024 * k];
        s += v.x + v.y + v.z + v.w;
    }
#pragma unroll
    for (int off = 32; off > 0; off >>= 1) s += __shfl_down(s, off, 64);
    __shared__ float sh[16];
    const int wave = threadIdx.x >> 6;
    const int lane = threadIdx.x & 63;
    if (lane == 0) sh[wave] = s;
    __syncthreads();
    if (threadIdx.x == 0) {
        float tot = 0.f;
#pragma unroll
        for (int w = 0; w < 16; ++w) tot += sh[w];
        out[0] = tot / (float)NROWS;
    }
}

extern "C" void kernel_launch(void* const* d_in, const int* in_sizes, int n_in,
                              void* d_out, int out_size, void* d_ws, size_t ws_size,
                              hipStream_t stream) {
    const float* recon = (const float*)d_in[0];
    const float* x     = (const float*)d_in[1];
    float* out   = (float*)d_out;
    float* theta = (float*)d_ws;   // NROWS floats = 64 KB scratch

    pal_row_theta<<<NROWS / WPB, BLOCK, 0, stream>>>(recon, x, theta);
    pal_mean<<<1, 1024, 0, stream>>>(theta, out);
}

// Round 3
// 46.613 us; speedup vs baseline: 1.3144x; 1.0181x over previous
//
#include <hip/hip_runtime.h>
#include <math.h>

#define D 2048
#define NROWS 16384
#define BLOCK 512            // 8 waves
#define WPB   (BLOCK / 64)   // 8 waves per block
#define RPW   2              // rows per wave
#define RPB   (WPB * RPW)    // 16 rows per block
#define GRID  (NROWS / RPB)  // 1024 blocks

__global__ __launch_bounds__(BLOCK) void pal_row_theta(const float* __restrict__ recon,
                                                       const float* __restrict__ x,
                                                       float* __restrict__ blockPartial) {
    const int wave = threadIdx.x >> 6;
    const int lane = threadIdx.x & 63;
    const int r0   = blockIdx.x * RPB + wave * RPW;   // this wave's two rows
    const int r1   = r0 + 1;

    const float4* a4 = reinterpret_cast<const float4*>(recon + (size_t)r0 * D);
    const float4* b4 = reinterpret_cast<const float4*>(x     + (size_t)r0 * D);
    const float4* c4 = reinterpret_cast<const float4*>(recon + (size_t)r1 * D);
    const float4* d4 = reinterpret_cast<const float4*>(x     + (size_t)r1 * D);

    float dot0 = 0.f, rr0 = 0.f, xx0 = 0.f;
    float dot1 = 0.f, rr1 = 0.f, xx1 = 0.f;

    // 512 float4 per row; 64 lanes x 8 float4 each; two independent rows
#pragma unroll
    for (int j = 0; j < 8; ++j) {
        float4 a = a4[lane + 64 * j];
        float4 b = b4[lane + 64 * j];
        float4 c = c4[lane + 64 * j];
        float4 e = d4[lane + 64 * j];
        dot0 += a.x * b.x + a.y * b.y + a.z * b.z + a.w * b.w;
        rr0  += a.x * a.x + a.y * a.y + a.z * a.z + a.w * a.w;
        xx0  += b.x * b.x + b.y * b.y + b.z * b.z + b.w * b.w;
        dot1 += c.x * e.x + c.y * e.y + c.z * e.z + c.w * e.w;
        rr1  += c.x * c.x + c.y * c.y + c.z * c.z + c.w * c.w;
        xx1  += e.x * e.x + e.y * e.y + e.z * e.z + e.w * e.w;
    }

#pragma unroll
    for (int off = 32; off > 0; off >>= 1) {
        dot0 += __shfl_down(dot0, off, 64);
        rr0  += __shfl_down(rr0,  off, 64);
        xx0  += __shfl_down(xx0,  off, 64);
        dot1 += __shfl_down(dot1, off, 64);
        rr1  += __shfl_down(rr1,  off, 64);
        xx1  += __shfl_down(xx1,  off, 64);
    }

    __shared__ float sh[WPB];
    if (lane == 0) {
        float c0 = dot0 / sqrtf(rr0 * xx0);
        float c1 = dot1 / sqrtf(rr1 * xx1);
        c0 = fminf(1.f, fmaxf(-1.f, c0));
        c1 = fminf(1.f, fmaxf(-1.f, c1));
        sh[wave] = acosf(c0) + acosf(c1);
    }
    __syncthreads();
    if (threadIdx.x == 0) {
        float s = 0.f;
#pragma unroll
        for (int w = 0; w < WPB; ++w) s += sh[w];
        blockPartial[blockIdx.x] = s;
    }
}

__global__ __launch_bounds__(256) void pal_mean(const float* __restrict__ blockPartial,
                                                float* __restrict__ out) {
    const float4* p4 = reinterpret_cast<const float4*>(blockPartial);  // 1024 floats = 256 float4
    float4 v = p4[threadIdx.x];
    float s = v.x + v.y + v.z + v.w;
#pragma unroll
    for (int off = 32; off > 0; off >>= 1) s += __shfl_down(s, off, 64);
    __shared__ float sh[4];
    const int wave = threadIdx.x >> 6;
    const int lane = threadIdx.x & 63;
    if (lane == 0) sh[wave] = s;
    __syncthreads();
    if (threadIdx.x == 0) {
        out[0] = (sh[0] + sh[1] + sh[2] + sh[3]) / (float)NROWS;
    }
}

extern "C" void kernel_launch(void* const* d_in, const int* in_sizes, int n_in,
                              void* d_out, int out_size, void* d_ws, size_t ws_size,
                              hipStream_t stream) {
    const float* recon = (const float*)d_in[0];
    const float* x     = (const float*)d_in[1];
    float* out     = (float*)d_out;
    float* partial = (float*)d_ws;   // GRID floats = 4 KB scratch

    pal_row_theta<<<GRID, BLOCK, 0, stream>>>(recon, x, partial);
    pal_mean<<<1, 256, 0, stream>>>(partial, out);
}

// Round 4
// 45.946 us; speedup vs baseline: 1.3335x; 1.0145x over previous
//
#include <hip/hip_runtime.h>
#include <math.h>

#define D 2048
#define NROWS 16384
#define BLOCK 256
#define WPB   (BLOCK / 64)     // 4 waves per block
#define GRID  2048             // 8192 waves total = exactly max residency (256 CU x 32)
#define TOTW  (GRID * WPB)     // 8192
#define RPW   (NROWS / TOTW)   // 2 rows per wave, grid-strided

__global__ __launch_bounds__(BLOCK) void pal_row_theta(const float* __restrict__ recon,
                                                       const float* __restrict__ x,
                                                       float* __restrict__ blockPartial) {
    const int wave = threadIdx.x >> 6;
    const int lane = threadIdx.x & 63;
    const int gw   = blockIdx.x * WPB + wave;

    float wsum = 0.f;

#pragma unroll 1
    for (int r = 0; r < RPW; ++r) {
        const int row = gw + r * TOTW;
        const float4* a4 = reinterpret_cast<const float4*>(recon + (size_t)row * D);
        const float4* b4 = reinterpret_cast<const float4*>(x     + (size_t)row * D);

        // Issue ALL 16 loads before any use: 16 independent 16B loads in flight.
        float4 A[8], B[8];
#pragma unroll
        for (int j = 0; j < 8; ++j) A[j] = a4[lane + 64 * j];
#pragma unroll
        for (int j = 0; j < 8; ++j) B[j] = b4[lane + 64 * j];

        float dot = 0.f, rr = 0.f, xx = 0.f;
#pragma unroll
        for (int j = 0; j < 8; ++j) {
            dot += A[j].x * B[j].x + A[j].y * B[j].y + A[j].z * B[j].z + A[j].w * B[j].w;
            rr  += A[j].x * A[j].x + A[j].y * A[j].y + A[j].z * A[j].z + A[j].w * A[j].w;
            xx  += B[j].x * B[j].x + B[j].y * B[j].y + B[j].z * B[j].z + B[j].w * B[j].w;
        }

#pragma unroll
        for (int off = 32; off > 0; off >>= 1) {
            dot += __shfl_down(dot, off, 64);
            rr  += __shfl_down(rr,  off, 64);
            xx  += __shfl_down(xx,  off, 64);
        }

        if (lane == 0) {
            float c = dot / sqrtf(rr * xx);
            c = fminf(1.f, fmaxf(-1.f, c));
            wsum += acosf(c);
        }
    }

    __shared__ float sh[WPB];
    if (lane == 0) sh[wave] = wsum;
    __syncthreads();
    if (threadIdx.x == 0) {
        float s = 0.f;
#pragma unroll
        for (int w = 0; w < WPB; ++w) s += sh[w];
        blockPartial[blockIdx.x] = s;
    }
}

__global__ __launch_bounds__(256) void pal_mean(const float* __restrict__ blockPartial,
                                                float* __restrict__ out) {
    // GRID = 2048 floats = 512 float4; 256 threads x 2 float4
    const float4* p4 = reinterpret_cast<const float4*>(blockPartial);
    float4 v0 = p4[threadIdx.x];
    float4 v1 = p4[threadIdx.x + 256];
    float s = v0.x + v0.y + v0.z + v0.w + v1.x + v1.y + v1.z + v1.w;
#pragma unroll
    for (int off = 32; off > 0; off >>= 1) s += __shfl_down(s, off, 64);
    __shared__ float sh[4];
    const int wave = threadIdx.x >> 6;
    const int lane = threadIdx.x & 63;
    if (lane == 0) sh[wave] = s;
    __syncthreads();
    if (threadIdx.x == 0) {
        out[0] = (sh[0] + sh[1] + sh[2] + sh[3]) / (float)NROWS;
    }
}

extern "C" void kernel_launch(void* const* d_in, const int* in_sizes, int n_in,
                              void* d_out, int out_size, void* d_ws, size_t ws_size,
                              hipStream_t stream) {
    const float* recon = (const float*)d_in[0];
    const float* x     = (const float*)d_in[1];
    float* out     = (float*)d_out;
    float* partial = (float*)d_ws;   // GRID floats = 8 KB scratch

    pal_row_theta<<<GRID, BLOCK, 0, stream>>>(recon, x, partial);
    pal_mean<<<1, 256, 0, stream>>>(partial, out);
}